// Round 6
// baseline (17.057 us; speedup 1.0000x reference)
//
#include <hip/hip_runtime.h>
#include <hip/hip_bf16.h>

// MahalanobisClassifier, fused single dispatch, A-fragments register-resident,
// all global loads issued before any VALU (max memory-level parallelism).
// out[b,c] = -( sum_d x^2*w - 2 sum_d x*(p*w) + s[c] ),  w = exp(ld)
// bf16 MFMA GEMM, K=512 concat: A'=[x^2 | x], B'=[w | -2*p*w], s in epilogue.
//
// Block: 512 threads (8 waves), tile 128 rows x 64 classes, grid (16,16).
// Wave w owns output rows w*16..+15 (full 64 cols); its A' fragments live in
// VGPRs (prep lane layout == MFMA A-frag layout: lane l -> row l&15,
// k (l>>4)*8+j — verified R1-R5). Only B' (64 KB) goes through LDS; ONE
// barrier; phases interleave into dual accumulator chains.

#define C_N 1000
#define D_N 256

typedef __attribute__((ext_vector_type(8))) short bf16x8;
typedef __attribute__((ext_vector_type(4))) float f32x4;

__device__ inline bf16x8 pack8(const float* v) {
  union { bf16x8 o; __hip_bfloat162 h[4]; } u;
#pragma unroll
  for (int j = 0; j < 4; ++j)
    u.h[j] = __float22bfloat162_rn(make_float2(v[2 * j], v[2 * j + 1]));
  return u.o;
}

__global__ __launch_bounds__(512, 2) void mahal_fused(
    const float* __restrict__ x, const float* __restrict__ p,
    const float* __restrict__ ld, float* __restrict__ out) {
  __shared__ short lB[4][16][64][8];   // 64 KB: 4 class-tiles x 16 ktiles, frag order
  __shared__ float s_lds[2][64];

  const int tid = threadIdx.x;
  const int w   = tid >> 6;        // wave 0..7
  const int l   = tid & 63;
  const int r16 = l & 15;
  const int hi  = l >> 4;
  const int bx  = blockIdx.x;      // rows bx*128..+127
  const int by  = blockIdx.y;      // cols by*64..+63

  // ---------------- issue ALL global loads first ----------------
  const int ct = w & 3;            // B: class-tile 0..3
  const int dh = w >> 2;           // B: d-half 0..1
  const int c  = by * 64 + ct * 16 + r16;
  const bool valid = (c < C_N);
  const int row = bx * 128 + w * 16 + r16;   // A: wave w owns row-tile w

  float4 lv4[4][2], pv4[4][2];     // B-side: 16 float4 (64 VGPR)
  float4 xv4[8][2];                // A-side: 16 float4 (64 VGPR)

#pragma unroll
  for (int t = 0; t < 4; ++t) {
    const int d = dh * 128 + t * 32 + hi * 8;
    const float* lp = ld + (size_t)(valid ? c : 0) * D_N + d;
    const float* pp = p  + (size_t)(valid ? c : 0) * D_N + d;
    lv4[t][0] = *reinterpret_cast<const float4*>(lp);
    lv4[t][1] = *reinterpret_cast<const float4*>(lp + 4);
    pv4[t][0] = *reinterpret_cast<const float4*>(pp);
    pv4[t][1] = *reinterpret_cast<const float4*>(pp + 4);
  }
#pragma unroll
  for (int t = 0; t < 8; ++t) {
    const int d = t * 32 + hi * 8;
    const float* xp = x + (size_t)row * D_N + d;
    xv4[t][0] = *reinterpret_cast<const float4*>(xp);
    xv4[t][1] = *reinterpret_cast<const float4*>(xp + 4);
  }

  // ---------------- B' VALU + LDS write (x loads still in flight) ----------------
  float sp = 0.f;
#pragma unroll
  for (int t = 0; t < 4; ++t) {
    float lvv[8] = {lv4[t][0].x, lv4[t][0].y, lv4[t][0].z, lv4[t][0].w,
                    lv4[t][1].x, lv4[t][1].y, lv4[t][1].z, lv4[t][1].w};
    float pvv[8] = {pv4[t][0].x, pv4[t][0].y, pv4[t][0].z, pv4[t][0].w,
                    pv4[t][1].x, pv4[t][1].y, pv4[t][1].z, pv4[t][1].w};
    float wv[8], pwv[8];
    if (valid) {
#pragma unroll
      for (int j = 0; j < 8; ++j) {
        float wj = __expf(lvv[j]);
        wv[j]  = wj;
        pwv[j] = -2.f * pvv[j] * wj;
        sp += pvv[j] * pvv[j] * wj;
      }
    } else {
#pragma unroll
      for (int j = 0; j < 8; ++j) { wv[j] = 0.f; pwv[j] = 0.f; }
    }
    *reinterpret_cast<bf16x8*>(&lB[ct][dh * 4 + t][l][0])     = pack8(wv);
    *reinterpret_cast<bf16x8*>(&lB[ct][8 + dh * 4 + t][l][0]) = pack8(pwv);
  }
  sp += __shfl_xor(sp, 16, 64);
  sp += __shfl_xor(sp, 32, 64);
  if (l < 16) s_lds[dh][ct * 16 + r16] = sp;

  // ---------------- A' pack into registers (frag order) ----------------
  bf16x8 aSq[8], aRaw[8];
#pragma unroll
  for (int t = 0; t < 8; ++t) {
    float v[8] = {xv4[t][0].x, xv4[t][0].y, xv4[t][0].z, xv4[t][0].w,
                  xv4[t][1].x, xv4[t][1].y, xv4[t][1].z, xv4[t][1].w};
    float sq[8];
#pragma unroll
    for (int j = 0; j < 8; ++j) sq[j] = v[j] * v[j];
    aSq[t]  = pack8(sq);
    aRaw[t] = pack8(v);
  }
  __syncthreads();   // B' + s visible; the ONLY barrier

  // ---------------- compute: wave tile 16x64, dual phase-interleaved acc ----------------
  f32x4 acc0[4], acc1[4];
#pragma unroll
  for (int n = 0; n < 4; ++n) { acc0[n] = {0.f,0.f,0.f,0.f}; acc1[n] = {0.f,0.f,0.f,0.f}; }

#pragma unroll
  for (int kt = 0; kt < 8; ++kt) {
#pragma unroll
    for (int n = 0; n < 4; ++n) {
      bf16x8 b0 = *reinterpret_cast<const bf16x8*>(&lB[n][kt][l][0]);
      bf16x8 b1 = *reinterpret_cast<const bf16x8*>(&lB[n][8 + kt][l][0]);
      acc0[n] = __builtin_amdgcn_mfma_f32_16x16x32_bf16(aSq[kt],  b0, acc0[n], 0, 0, 0);
      acc1[n] = __builtin_amdgcn_mfma_f32_16x16x32_bf16(aRaw[kt], b1, acc1[n], 0, 0, 0);
    }
  }

  // ---------------- epilogue ----------------
  // C/D layout: col = lane&15, row = (lane>>4)*4 + reg   [verified R1-R5]
  const int rowbase = bx * 128 + w * 16 + hi * 4;
#pragma unroll
  for (int n = 0; n < 4; ++n) {
    const int col = by * 64 + n * 16 + r16;
    if (col < C_N) {
      const int ci = n * 16 + r16;
      const float sc = s_lds[0][ci] + s_lds[1][ci];
#pragma unroll
      for (int r = 0; r < 4; ++r)
        out[(size_t)(rowbase + r) * C_N + col] = -(acc0[n][r] + acc1[n][r] + sc);
    }
  }
}

extern "C" void kernel_launch(void* const* d_in, const int* in_sizes, int n_in,
                              void* d_out, int out_size, void* d_ws, size_t ws_size,
                              hipStream_t stream) {
  const float* x  = (const float*)d_in[0];
  const float* p  = (const float*)d_in[1];
  const float* ld = (const float*)d_in[2];
  float* out = (float*)d_out;
  mahal_fused<<<dim3(16, 16), 512, 0, stream>>>(x, p, ld, out);
}

// Round 7
// 16.087 us; speedup vs baseline: 1.0603x; 1.0603x over previous
//
#include <hip/hip_runtime.h>
#include <hip/hip_bf16.h>

// MahalanobisClassifier, fused single dispatch, A-fragments register-resident.
// out[b,c] = -( sum_d x^2*w - 2 sum_d x*(p*w) + s[c] ),  w = exp(ld)
// bf16 MFMA GEMM, K=512 concat: A'=[x^2 | x], B'=[w | -2*p*w], s in epilogue.
//
// Block: 512 threads (8 waves), tile 128 rows x 64 classes, grid (16,16).
// Wave w owns output rows w*16..+15 (full 64 cols): its A' fragments are packed
// directly into VGPRs during prep (prep lane layout == MFMA A-frag layout:
// lane l -> row l&15, k (l>>4)*8+j — verified R1-R6). Only B' (64 KB) goes
// through LDS; ONE barrier; phase 0 (x^2 vs w) and phase 1 (x vs -2pw)
// interleave into dual accumulator chains with no intermediate sync.
// (R6 lesson: do NOT hoist all loads above the VALU chain — VGPR pressure
// regresses it; source order here is the measured-best R5 configuration.)

#define C_N 1000
#define D_N 256

typedef __attribute__((ext_vector_type(8))) short bf16x8;
typedef __attribute__((ext_vector_type(4))) float f32x4;

__device__ inline bf16x8 pack8(const float* v) {
  union { bf16x8 o; __hip_bfloat162 h[4]; } u;
#pragma unroll
  for (int j = 0; j < 4; ++j)
    u.h[j] = __float22bfloat162_rn(make_float2(v[2 * j], v[2 * j + 1]));
  return u.o;
}

__global__ __launch_bounds__(512, 2) void mahal_fused(
    const float* __restrict__ x, const float* __restrict__ p,
    const float* __restrict__ ld, float* __restrict__ out) {
  __shared__ short lB[4][16][64][8];   // 64 KB: 4 class-tiles x 16 ktiles, frag order
  __shared__ float s_lds[2][64];

  const int tid = threadIdx.x;
  const int w   = tid >> 6;        // wave 0..7
  const int l   = tid & 63;
  const int r16 = l & 15;
  const int hi  = l >> 4;
  const int bx  = blockIdx.x;      // rows bx*128..+127
  const int by  = blockIdx.y;      // cols by*64..+63

  // ---------------- B' prep: waves split (class-tile, d-half) ----------------
  {
    const int ct = w & 3;          // class-tile 0..3
    const int dh = w >> 2;         // d-half 0..1
    const int c  = by * 64 + ct * 16 + r16;
    const bool valid = (c < C_N);
    float sp = 0.f;
#pragma unroll
    for (int t = 0; t < 4; ++t) {
      const int d = dh * 128 + t * 32 + hi * 8;
      float wv[8], pwv[8];
      if (valid) {
        const float* lp = ld + (size_t)c * D_N + d;
        const float* pp = p  + (size_t)c * D_N + d;
        float4 l0 = *reinterpret_cast<const float4*>(lp);
        float4 l1 = *reinterpret_cast<const float4*>(lp + 4);
        float4 p0 = *reinterpret_cast<const float4*>(pp);
        float4 p1 = *reinterpret_cast<const float4*>(pp + 4);
        float lv[8] = {l0.x,l0.y,l0.z,l0.w,l1.x,l1.y,l1.z,l1.w};
        float pv[8] = {p0.x,p0.y,p0.z,p0.w,p1.x,p1.y,p1.z,p1.w};
#pragma unroll
        for (int j = 0; j < 8; ++j) {
          float wj = __expf(lv[j]);
          wv[j]  = wj;
          pwv[j] = -2.f * pv[j] * wj;
          sp += pv[j] * pv[j] * wj;
        }
      } else {
#pragma unroll
        for (int j = 0; j < 8; ++j) { wv[j] = 0.f; pwv[j] = 0.f; }
      }
      *reinterpret_cast<bf16x8*>(&lB[ct][dh * 4 + t][l][0])     = pack8(wv);
      *reinterpret_cast<bf16x8*>(&lB[ct][8 + dh * 4 + t][l][0]) = pack8(pwv);
    }
    sp += __shfl_xor(sp, 16, 64);
    sp += __shfl_xor(sp, 32, 64);
    if (l < 16) s_lds[dh][ct * 16 + r16] = sp;
  }

  // ---------------- A' prep: straight into registers (frag order) ----------------
  bf16x8 aSq[8], aRaw[8];
  {
    const int row = bx * 128 + w * 16 + r16;   // wave w owns row-tile w
#pragma unroll
    for (int t = 0; t < 8; ++t) {
      const int d = t * 32 + hi * 8;
      const float* xp = x + (size_t)row * D_N + d;
      float4 v0 = *reinterpret_cast<const float4*>(xp);
      float4 v1 = *reinterpret_cast<const float4*>(xp + 4);
      float v[8] = {v0.x,v0.y,v0.z,v0.w,v1.x,v1.y,v1.z,v1.w};
      float sq[8];
#pragma unroll
      for (int j = 0; j < 8; ++j) sq[j] = v[j] * v[j];
      aSq[t]  = pack8(sq);
      aRaw[t] = pack8(v);
    }
  }
  __syncthreads();   // B' + s visible; the ONLY barrier

  // ---------------- compute: wave tile 16x64, dual phase-interleaved acc ----------------
  f32x4 acc0[4], acc1[4];
#pragma unroll
  for (int n = 0; n < 4; ++n) { acc0[n] = {0.f,0.f,0.f,0.f}; acc1[n] = {0.f,0.f,0.f,0.f}; }

#pragma unroll
  for (int kt = 0; kt < 8; ++kt) {
#pragma unroll
    for (int n = 0; n < 4; ++n) {
      bf16x8 b0 = *reinterpret_cast<const bf16x8*>(&lB[n][kt][l][0]);
      bf16x8 b1 = *reinterpret_cast<const bf16x8*>(&lB[n][8 + kt][l][0]);
      acc0[n] = __builtin_amdgcn_mfma_f32_16x16x32_bf16(aSq[kt],  b0, acc0[n], 0, 0, 0);
      acc1[n] = __builtin_amdgcn_mfma_f32_16x16x32_bf16(aRaw[kt], b1, acc1[n], 0, 0, 0);
    }
  }

  // ---------------- epilogue ----------------
  // C/D layout: col = lane&15, row = (lane>>4)*4 + reg   [verified R1-R6]
  const int rowbase = bx * 128 + w * 16 + hi * 4;
#pragma unroll
  for (int n = 0; n < 4; ++n) {
    const int col = by * 64 + n * 16 + r16;
    if (col < C_N) {
      const int ci = n * 16 + r16;
      const float sc = s_lds[0][ci] + s_lds[1][ci];
#pragma unroll
      for (int r = 0; r < 4; ++r)
        out[(size_t)(rowbase + r) * C_N + col] = -(acc0[n][r] + acc1[n][r] + sc);
    }
  }
}

extern "C" void kernel_launch(void* const* d_in, const int* in_sizes, int n_in,
                              void* d_out, int out_size, void* d_ws, size_t ws_size,
                              hipStream_t stream) {
  const float* x  = (const float*)d_in[0];
  const float* p  = (const float*)d_in[1];
  const float* ld = (const float*)d_in[2];
  float* out = (float*)d_out;
  mahal_fused<<<dim3(16, 16), 512, 0, stream>>>(x, p, ld, out);
}